// Round 1
// baseline (1409.126 us; speedup 1.0000x reference)
//
#include <hip/hip_runtime.h>

typedef unsigned int u32;
typedef unsigned short u16;

typedef _Float16 f16x8 __attribute__((ext_vector_type(8)));
typedef float    f32x4 __attribute__((ext_vector_type(4)));

constexpr int NN = 100000;   // nodes
constexpr int NE = 1600000;  // edges
constexpr int NG = 256;      // graphs
constexpr int DH = 128;      // hidden dim
constexpr int NL = 4;        // GIN layers

// d_out layout (fp32 elements)
constexpr long long OFF_EMB  = 0;                       // 5*NN*128
constexpr long long OFF_PS   = 64000000LL;              // 256*128
constexpr long long OFF_L1   = OFF_PS  + (long long)NG*DH;
constexpr long long OFF_L1D  = OFF_L1  + (long long)NG*DH;
constexpr long long OFF_L2   = OFF_L1D + (long long)NG*DH;
constexpr long long OFF_SOFT = OFF_L2  + (long long)NG*8;

__device__ __forceinline__ u16 f2h(float f) {
    union { _Float16 h; u16 s; } c; c.h = (_Float16)f; return c.s;
}
__device__ __forceinline__ float h2f(u16 s) {
    union { u16 s; _Float16 h; } c; c.s = s; return (float)c.h;
}

union U16x8 { uint4 u; f16x8 h; };

// ---------------- fp32 -> fp16 conversion of x ----------------
__global__ __launch_bounds__(256) void k_conv(const float* __restrict__ x,
                                              u16* __restrict__ o, int n4) {
    int i = blockIdx.x * 256 + threadIdx.x;
    if (i >= n4) return;
    float4 v = ((const float4*)x)[i];
    uint2 p;
    p.x = (u32)f2h(v.x) | ((u32)f2h(v.y) << 16);
    p.y = (u32)f2h(v.z) | ((u32)f2h(v.w) << 16);
    ((uint2*)o)[i] = p;
}

// ---------------- CSR build ----------------
__global__ __launch_bounds__(256) void k_hist(const int* __restrict__ ei, int* __restrict__ cnt) {
    int e = blockIdx.x * 256 + threadIdx.x;
    if (e < NE) atomicAdd(&cnt[ei[e]], 1);
}

__global__ __launch_bounds__(256) void k_scan1(const int* __restrict__ cnt,
                                               int* __restrict__ rp, int* __restrict__ bsum) {
    __shared__ int sd[256];
    int t = threadIdx.x;
    int base = blockIdx.x * 1024 + t * 4;
    int v0 = (base + 0 < NN) ? cnt[base + 0] : 0;
    int v1 = (base + 1 < NN) ? cnt[base + 1] : 0;
    int v2 = (base + 2 < NN) ? cnt[base + 2] : 0;
    int v3 = (base + 3 < NN) ? cnt[base + 3] : 0;
    int s = v0 + v1 + v2 + v3;
    sd[t] = s; __syncthreads();
    for (int off = 1; off < 256; off <<= 1) {
        int x = (t >= off) ? sd[t - off] : 0;
        __syncthreads();
        sd[t] += x;
        __syncthreads();
    }
    int e = sd[t] - s;
    if (base + 0 < NN) rp[base + 0] = e; e += v0;
    if (base + 1 < NN) rp[base + 1] = e; e += v1;
    if (base + 2 < NN) rp[base + 2] = e; e += v2;
    if (base + 3 < NN) rp[base + 3] = e;
    if (t == 255) bsum[blockIdx.x] = sd[255];
}

__global__ void k_scan2(int* __restrict__ bsum, int nb) {
    __shared__ int sd[128];
    int t = threadIdx.x;
    int v = (t < nb) ? bsum[t] : 0;
    sd[t] = v; __syncthreads();
    for (int off = 1; off < 128; off <<= 1) {
        int x = (t >= off) ? sd[t - off] : 0;
        __syncthreads();
        sd[t] += x;
        __syncthreads();
    }
    if (t < nb) bsum[t] = sd[t] - v;
}

__global__ __launch_bounds__(256) void k_scan3(int* __restrict__ rp, const int* __restrict__ bsum) {
    int t = threadIdx.x;
    int base = blockIdx.x * 1024 + t * 4;
    int add = bsum[blockIdx.x];
    #pragma unroll
    for (int j = 0; j < 4; ++j)
        if (base + j < NN) rp[base + j] += add;
    if (blockIdx.x == 0 && t == 0) rp[NN] = NE;
}

__global__ __launch_bounds__(256) void k_scatter(const int* __restrict__ ei,
                                                 const float* __restrict__ mask,
                                                 const int* __restrict__ rp,
                                                 int* __restrict__ cur,
                                                 int* __restrict__ ci,
                                                 float* __restrict__ wv) {
    int e = blockIdx.x * 256 + threadIdx.x;
    if (e >= NE) return;
    int d = ei[e];
    int pos = rp[d] + atomicAdd(&cur[d], 1);
    ci[pos] = ei[NE + e];
    wv[pos] = mask[e];
}

// ---------------- aggregation: pooled = agg + (1+eps)*h, fp16 in/out ----------------
__global__ __launch_bounds__(256) void k_agg(const u16* __restrict__ h,
                                             u16* __restrict__ pooled,
                                             const int* __restrict__ rp,
                                             const int* __restrict__ ci,
                                             const float* __restrict__ wv,
                                             const float* __restrict__ eps, int layer) {
    int lane = threadIdx.x & 63;
    int node = (blockIdx.x * 256 + threadIdx.x) >> 6;
    if (node >= NN) return;
    const u32* h32 = (const u32*)h;
    float a0 = 0.f, a1 = 0.f;
    int e0 = rp[node], e1 = rp[node + 1];
    for (int e = e0; e < e1; ++e) {
        int s = ci[e];
        float w = wv[e];
        u32 v = h32[(size_t)s * 64 + lane];
        a0 += w * h2f((u16)(v & 0xffff));
        a1 += w * h2f((u16)(v >> 16));
    }
    float ep = 1.f + eps[layer];
    u32 v = h32[(size_t)node * 64 + lane];
    a0 += ep * h2f((u16)(v & 0xffff));
    a1 += ep * h2f((u16)(v >> 16));
    u32 o = (u32)f2h(a0) | ((u32)f2h(a1) << 16);
    ((u32*)pooled)[(size_t)node * 64 + lane] = o;
}

// ---------------- GEMM: out[M,128] = A[M,128] @ W^T + b (fp16 MFMA, W split hi/lo) ----
// Each wave owns a 32-col slice (nt pair = wid&3); W fragments live in VGPRs.
__global__ __launch_bounds__(256) void k_gemm(const u16* __restrict__ A,
                                              const float* __restrict__ W,
                                              const float* __restrict__ bias,
                                              u16* __restrict__ outh,
                                              float* __restrict__ outf,
                                              int relu, int M) {
    const int lane = threadIdx.x & 63;
    const int wid = (blockIdx.x * 256 + threadIdx.x) >> 6;
    const int nwaves = (gridDim.x * 256) >> 6;
    const int m = lane & 15, q = lane >> 4;
    const int pair = wid & 3;          // cols [pair*32, pair*32+32)
    const int tile0 = wid >> 2;
    const int tstride = nwaves >> 2;

    // Load W fragments once: B[k][n] = W[n][k]; lane holds n=lane&15, k=q*8+j.
    f16x8 bhi[2][4], blo[2][4];
    float bs[2];
    #pragma unroll
    for (int t = 0; t < 2; ++t) {
        int n = pair * 32 + t * 16 + m;
        const float* wr = W + (size_t)n * 128 + q * 8;
        bs[t] = bias[n];
        #pragma unroll
        for (int kb = 0; kb < 4; ++kb) {
            float4 f0 = *(const float4*)(wr + kb * 32);
            float4 f1 = *(const float4*)(wr + kb * 32 + 4);
            float f[8] = {f0.x, f0.y, f0.z, f0.w, f1.x, f1.y, f1.z, f1.w};
            f16x8 hi, lo;
            #pragma unroll
            for (int j = 0; j < 8; ++j) {
                _Float16 h = (_Float16)f[j];
                hi[j] = h;
                lo[j] = (_Float16)(f[j] - (float)h);
            }
            bhi[t][kb] = hi;
            blo[t][kb] = lo;
        }
    }

    const int ntiles = M / 16;
    for (int tile = tile0; tile < ntiles; tile += tstride) {
        int row0 = tile * 16;
        const uint4* ap = (const uint4*)(A + (size_t)(row0 + m) * 128 + q * 8);
        f16x8 af[4];
        #pragma unroll
        for (int kb = 0; kb < 4; ++kb) {
            U16x8 u; u.u = ap[kb * 4];  // kb*32 halves = kb*4 uint4
            af[kb] = u.h;
        }
        #pragma unroll
        for (int t = 0; t < 2; ++t) {
            f32x4 acc = {0.f, 0.f, 0.f, 0.f};
            #pragma unroll
            for (int kb = 0; kb < 4; ++kb) {
                acc = __builtin_amdgcn_mfma_f32_16x16x32_f16(af[kb], bhi[t][kb], acc, 0, 0, 0);
                acc = __builtin_amdgcn_mfma_f32_16x16x32_f16(af[kb], blo[t][kb], acc, 0, 0, 0);
            }
            int col = pair * 32 + t * 16 + m;
            #pragma unroll
            for (int r = 0; r < 4; ++r) {
                int row = row0 + q * 4 + r;   // C/D: col=lane&15, row=q*4+reg (m89/m91)
                float v = acc[r] + bs[t];
                if (relu) v = fmaxf(v, 0.f);
                outh[(size_t)row * 128 + col] = f2h(v);
                if (outf) outf[(size_t)row * 128 + col] = v;
            }
        }
    }
}

// ---------------- graph pooling: ps_tmp[g][d] += sum over nodes/embeds ----------------
__device__ __forceinline__ int lbound(const int* b, int n, int v) {
    int lo = 0, hi = n;
    while (lo < hi) { int mid = (lo + hi) >> 1; if (b[mid] < v) lo = mid + 1; else hi = mid; }
    return lo;
}

__global__ __launch_bounds__(128) void k_pool_partial(const float* __restrict__ embeds,
                                                      const int* __restrict__ batch,
                                                      float* __restrict__ ps_tmp) {
    int g = blockIdx.x >> 3, s = blockIdx.x & 7, t = threadIdx.x;
    int lo = lbound(batch, NN, g);
    int hi = lbound(batch, NN, g + 1);
    float acc = 0.f;
    for (int n = lo + s; n < hi; n += 8) {
        #pragma unroll
        for (int e = 0; e < 5; ++e)
            acc += embeds[(size_t)e * NN * 128 + (size_t)n * 128 + t];
    }
    atomicAdd(&ps_tmp[g * 128 + t], acc);
}

// ---------------- head: pooled_sum -> lin1 -> lin2 -> softmax ----------------
__global__ __launch_bounds__(128) void k_final(const float* __restrict__ ps_tmp,
                                               const float* __restrict__ W1, const float* __restrict__ b1,
                                               const float* __restrict__ W2, const float* __restrict__ b2,
                                               float* __restrict__ out) {
    int g = blockIdx.x, t = threadIdx.x;
    __shared__ float ps[128], l1[128], l2[8];
    float v = ps_tmp[g * 128 + t];
    ps[t] = v;
    out[OFF_PS + (size_t)g * 128 + t] = v;
    __syncthreads();
    float a = b1[t];
    #pragma unroll 8
    for (int k = 0; k < 128; ++k) a += ps[k] * W1[t * 128 + k];
    a = fmaxf(a, 0.f);
    l1[t] = a;
    out[OFF_L1  + (size_t)g * 128 + t] = a;
    out[OFF_L1D + (size_t)g * 128 + t] = a;
    __syncthreads();
    if (t < 8) {
        float a2 = b2[t];
        #pragma unroll 8
        for (int k = 0; k < 128; ++k) a2 += l1[k] * W2[t * 128 + k];
        l2[t] = a2;
        out[OFF_L2 + (size_t)g * 8 + t] = a2;
    }
    __syncthreads();
    if (t == 0) {
        float mx = l2[0];
        for (int j = 1; j < 8; ++j) mx = fmaxf(mx, l2[j]);
        float e[8], s = 0.f;
        for (int j = 0; j < 8; ++j) { e[j] = __expf(l2[j] - mx); s += e[j]; }
        float inv = 1.f / s;
        for (int j = 0; j < 8; ++j) out[OFF_SOFT + (size_t)g * 8 + j] = e[j] * inv;
    }
}

extern "C" void kernel_launch(void* const* d_in, const int* in_sizes, int n_in,
                              void* d_out, int out_size, void* d_ws, size_t ws_size,
                              hipStream_t stream) {
    const float* x       = (const float*)d_in[0];
    const int*   ei      = (const int*)d_in[1];
    const float* emask   = (const float*)d_in[2];
    const int*   batch   = (const int*)d_in[3];
    const float* eps     = (const float*)d_in[4];
    const float* W_first = (const float*)d_in[5];
    const float* b_first = (const float*)d_in[6];
    const float* gin_W   = (const float*)d_in[7];
    const float* gin_b   = (const float*)d_in[8];
    const float* W1      = (const float*)d_in[9];
    const float* b1      = (const float*)d_in[10];
    const float* W2      = (const float*)d_in[11];
    const float* b2      = (const float*)d_in[12];
    float* out = (float*)d_out;

    char* ws = (char*)d_ws;
    const size_t HB = (size_t)NN * 128 * 2;       // 25.6 MB per fp16 node buffer
    u16* buf0 = (u16*)(ws);
    u16* buf1 = (u16*)(ws + HB);
    u16* buf2 = (u16*)(ws + 2 * HB);
    size_t o = 3 * HB;
    int* cnt  = (int*)(ws + o); o += 400000;
    int* rp   = (int*)(ws + o); o += 400064;      // NN+1 ints, padded
    int* cur  = (int*)(ws + o); o += 400000;
    int* bsum = (int*)(ws + o); o += 512;
    int* ci   = (int*)(ws + o); o += (size_t)NE * 4;
    float* wv = (float*)(ws + o); o += (size_t)NE * 4;
    float* ps_tmp = (float*)(ws + o); o += (size_t)NG * DH * 4;

    hipMemsetAsync(cnt, 0, NN * sizeof(int), stream);
    hipMemsetAsync(cur, 0, NN * sizeof(int), stream);
    hipMemsetAsync(ps_tmp, 0, NG * DH * sizeof(float), stream);

    // x -> fp16 (buf1)
    k_conv<<<12500, 256, 0, stream>>>(x, buf1, NN * 128 / 4);

    // CSR build
    k_hist<<<NE / 256, 256, 0, stream>>>(ei, cnt);
    k_scan1<<<98, 256, 0, stream>>>(cnt, rp, bsum);
    k_scan2<<<1, 128, 0, stream>>>(bsum, 98);
    k_scan3<<<98, 256, 0, stream>>>(rp, bsum);
    k_scatter<<<NE / 256, 256, 0, stream>>>(ei, emask, rp, cur, ci, wv);

    // first linear: buf1 -> buf0 (+ embeds[0])
    k_gemm<<<1024, 256, 0, stream>>>(buf1, W_first, b_first, buf0,
                                     out + OFF_EMB, 0, NN);

    for (int l = 0; l < NL; ++l) {
        k_agg<<<NN / 4, 256, 0, stream>>>(buf0, buf1, rp, ci, wv, eps, l);
        k_gemm<<<1024, 256, 0, stream>>>(buf1, gin_W + (size_t)(l * 2 + 0) * 128 * 128,
                                         gin_b + (size_t)(l * 2 + 0) * 128,
                                         buf2, nullptr, 1, NN);
        k_gemm<<<1024, 256, 0, stream>>>(buf2, gin_W + (size_t)(l * 2 + 1) * 128 * 128,
                                         gin_b + (size_t)(l * 2 + 1) * 128,
                                         buf0, out + OFF_EMB + (size_t)(l + 1) * NN * 128, 1, NN);
    }

    k_pool_partial<<<NG * 8, 128, 0, stream>>>(out + OFF_EMB, batch, ps_tmp);
    k_final<<<NG, 128, 0, stream>>>(ps_tmp, W1, b1, W2, b2, out);
}

// Round 2
// 1080.414 us; speedup vs baseline: 1.3042x; 1.3042x over previous
//
#include <hip/hip_runtime.h>

typedef unsigned int u32;
typedef unsigned short u16;

typedef _Float16 f16x8 __attribute__((ext_vector_type(8)));
typedef float    f32x4 __attribute__((ext_vector_type(4)));

constexpr int NN = 100000;   // nodes
constexpr int NE = 1600000;  // edges
constexpr int NG = 256;      // graphs
constexpr int DH = 128;      // hidden dim
constexpr int NL = 4;        // GIN layers

// d_out layout (fp32 elements)
constexpr long long OFF_EMB  = 0;                       // 5*NN*128
constexpr long long OFF_PS   = 64000000LL;              // 256*128
constexpr long long OFF_L1   = OFF_PS  + (long long)NG*DH;
constexpr long long OFF_L1D  = OFF_L1  + (long long)NG*DH;
constexpr long long OFF_L2   = OFF_L1D + (long long)NG*DH;
constexpr long long OFF_SOFT = OFF_L2  + (long long)NG*8;

__device__ __forceinline__ u16 f2h(float f) {
    union { _Float16 h; u16 s; } c; c.h = (_Float16)f; return c.s;
}
__device__ __forceinline__ float h2f(u16 s) {
    union { u16 s; _Float16 h; } c; c.s = s; return (float)c.h;
}

union U16x8 { uint4 u; f16x8 h; u16 s[8]; };

// ---------------- CSR build ----------------
__global__ __launch_bounds__(256) void k_hist(const int* __restrict__ ei, int* __restrict__ cnt) {
    int e = blockIdx.x * 256 + threadIdx.x;
    if (e < NE) atomicAdd(&cnt[ei[e]], 1);
}

__global__ __launch_bounds__(256) void k_scan1(const int* __restrict__ cnt,
                                               int* __restrict__ rp, int* __restrict__ bsum) {
    __shared__ int sd[256];
    int t = threadIdx.x;
    int base = blockIdx.x * 1024 + t * 4;
    int v0 = (base + 0 < NN) ? cnt[base + 0] : 0;
    int v1 = (base + 1 < NN) ? cnt[base + 1] : 0;
    int v2 = (base + 2 < NN) ? cnt[base + 2] : 0;
    int v3 = (base + 3 < NN) ? cnt[base + 3] : 0;
    int s = v0 + v1 + v2 + v3;
    sd[t] = s; __syncthreads();
    for (int off = 1; off < 256; off <<= 1) {
        int x = (t >= off) ? sd[t - off] : 0;
        __syncthreads();
        sd[t] += x;
        __syncthreads();
    }
    int e = sd[t] - s;
    if (base + 0 < NN) rp[base + 0] = e; e += v0;
    if (base + 1 < NN) rp[base + 1] = e; e += v1;
    if (base + 2 < NN) rp[base + 2] = e; e += v2;
    if (base + 3 < NN) rp[base + 3] = e;
    if (t == 255) bsum[blockIdx.x] = sd[255];
}

__global__ void k_scan2(int* __restrict__ bsum, int nb) {
    __shared__ int sd[128];
    int t = threadIdx.x;
    int v = (t < nb) ? bsum[t] : 0;
    sd[t] = v; __syncthreads();
    for (int off = 1; off < 128; off <<= 1) {
        int x = (t >= off) ? sd[t - off] : 0;
        __syncthreads();
        sd[t] += x;
        __syncthreads();
    }
    if (t < nb) bsum[t] = sd[t] - v;
}

__global__ __launch_bounds__(256) void k_scan3(int* __restrict__ rp, const int* __restrict__ bsum) {
    int t = threadIdx.x;
    int base = blockIdx.x * 1024 + t * 4;
    int add = bsum[blockIdx.x];
    #pragma unroll
    for (int j = 0; j < 4; ++j)
        if (base + j < NN) rp[base + j] += add;
    if (blockIdx.x == 0 && t == 0) rp[NN] = NE;
}

__global__ __launch_bounds__(256) void k_scatter(const int* __restrict__ ei,
                                                 const float* __restrict__ mask,
                                                 const int* __restrict__ rp,
                                                 int* __restrict__ cur,
                                                 int* __restrict__ ci,
                                                 float* __restrict__ wv) {
    int e = blockIdx.x * 256 + threadIdx.x;
    if (e >= NE) return;
    int d = ei[e];
    int pos = rp[d] + atomicAdd(&cur[d], 1);
    ci[pos] = ei[NE + e];
    wv[pos] = mask[e];
}

// ---------------- aggregation: pooled = agg + (1+eps)*h, fp16 in/out ----------------
// One 64-lane wave per node; 4-wide edge unroll with aligned int4/float4 index
// loads and 4 independent row gathers in flight (MLP for L3 latency).
__global__ __launch_bounds__(256) void k_agg(const u16* __restrict__ h,
                                             u16* __restrict__ pooled,
                                             const int* __restrict__ rp,
                                             const int* __restrict__ ci,
                                             const float* __restrict__ wv,
                                             const float* __restrict__ eps, int layer) {
    int lane = threadIdx.x & 63;
    int node = (blockIdx.x * 256 + threadIdx.x) >> 6;
    if (node >= NN) return;
    const u32* h32 = (const u32*)h;
    float a0 = 0.f, a1 = 0.f;
    int e0 = rp[node], e1 = rp[node + 1];
    int e = e0;
    int ehead = (e0 + 3) & ~3;
    if (ehead > e1) ehead = e1;
    for (; e < ehead; ++e) {
        int s = ci[e];
        float w = wv[e];
        u32 v = h32[s * 64 + lane];
        a0 += w * h2f((u16)(v & 0xffff));
        a1 += w * h2f((u16)(v >> 16));
    }
    for (; e + 4 <= e1; e += 4) {
        int4  s4 = *(const int4*)(ci + e);
        float4 w4 = *(const float4*)(wv + e);
        u32 v0 = h32[s4.x * 64 + lane];
        u32 v1 = h32[s4.y * 64 + lane];
        u32 v2 = h32[s4.z * 64 + lane];
        u32 v3 = h32[s4.w * 64 + lane];
        a0 += w4.x * h2f((u16)(v0 & 0xffff)) + w4.y * h2f((u16)(v1 & 0xffff))
            + w4.z * h2f((u16)(v2 & 0xffff)) + w4.w * h2f((u16)(v3 & 0xffff));
        a1 += w4.x * h2f((u16)(v0 >> 16)) + w4.y * h2f((u16)(v1 >> 16))
            + w4.z * h2f((u16)(v2 >> 16)) + w4.w * h2f((u16)(v3 >> 16));
    }
    for (; e < e1; ++e) {
        int s = ci[e];
        float w = wv[e];
        u32 v = h32[s * 64 + lane];
        a0 += w * h2f((u16)(v & 0xffff));
        a1 += w * h2f((u16)(v >> 16));
    }
    float ep = 1.f + eps[layer];
    u32 v = h32[node * 64 + lane];
    a0 += ep * h2f((u16)(v & 0xffff));
    a1 += ep * h2f((u16)(v >> 16));
    u32 o = (u32)f2h(a0) | ((u32)f2h(a1) << 16);
    ((u32*)pooled)[(size_t)node * 64 + lane] = o;
}

// ---------------- GEMM: out[M,128] = A[M,128] @ W^T + b (fp16 MFMA, W split hi/lo) ----
// Each wave owns a 32-col slice; W fragments in VGPRs; epilogue staged through
// LDS (stride 36 floats -> 2-way banks, 16B-aligned rows) for coalesced stores.
__global__ __launch_bounds__(256) void k_gemm(const u16* __restrict__ A,
                                              const float* __restrict__ Af32,
                                              const float* __restrict__ W,
                                              const float* __restrict__ bias,
                                              u16* __restrict__ outh,
                                              float* __restrict__ outf,
                                              int relu, int M) {
    __shared__ float stage[4][16 * 36];
    float* st = stage[threadIdx.x >> 6];
    const int lane = threadIdx.x & 63;
    const int wid = (blockIdx.x * 256 + threadIdx.x) >> 6;
    const int nwaves = (gridDim.x * 256) >> 6;
    const int m = lane & 15, q = lane >> 4;
    const int pair = wid & 3;          // cols [pair*32, pair*32+32)
    const int tile0 = wid >> 2;
    const int tstride = nwaves >> 2;

    // Load W fragments once: B[k][n] = W[n][k]; lane holds n=lane&15, k=q*8+j.
    f16x8 bhi[2][4], blo[2][4];
    float bs[2];
    #pragma unroll
    for (int t = 0; t < 2; ++t) {
        int n = pair * 32 + t * 16 + m;
        const float* wr = W + (size_t)n * 128 + q * 8;
        bs[t] = bias[n];
        #pragma unroll
        for (int kb = 0; kb < 4; ++kb) {
            float4 f0 = *(const float4*)(wr + kb * 32);
            float4 f1 = *(const float4*)(wr + kb * 32 + 4);
            float f[8] = {f0.x, f0.y, f0.z, f0.w, f1.x, f1.y, f1.z, f1.w};
            f16x8 hi, lo;
            #pragma unroll
            for (int j = 0; j < 8; ++j) {
                _Float16 h = (_Float16)f[j];
                hi[j] = h;
                lo[j] = (_Float16)(f[j] - (float)h);
            }
            bhi[t][kb] = hi;
            blo[t][kb] = lo;
        }
    }

    const int rdrow = lane >> 2, rdcg = lane & 3;   // epilogue readback mapping
    const int ntiles = M / 16;
    for (int tile = tile0; tile < ntiles; tile += tstride) {
        int row0 = tile * 16;
        f16x8 af[4];
        if (Af32) {
            const float* ap = Af32 + (size_t)(row0 + m) * 128 + q * 8;
            #pragma unroll
            for (int kb = 0; kb < 4; ++kb) {
                float4 f0 = *(const float4*)(ap + kb * 32);
                float4 f1 = *(const float4*)(ap + kb * 32 + 4);
                f16x8 h;
                h[0] = (_Float16)f0.x; h[1] = (_Float16)f0.y;
                h[2] = (_Float16)f0.z; h[3] = (_Float16)f0.w;
                h[4] = (_Float16)f1.x; h[5] = (_Float16)f1.y;
                h[6] = (_Float16)f1.z; h[7] = (_Float16)f1.w;
                af[kb] = h;
            }
        } else {
            const uint4* ap = (const uint4*)(A + (size_t)(row0 + m) * 128 + q * 8);
            #pragma unroll
            for (int kb = 0; kb < 4; ++kb) {
                U16x8 u; u.u = ap[kb * 4];
                af[kb] = u.h;
            }
        }
        f32x4 acc[2] = {{0.f, 0.f, 0.f, 0.f}, {0.f, 0.f, 0.f, 0.f}};
        #pragma unroll
        for (int t = 0; t < 2; ++t)
            #pragma unroll
            for (int kb = 0; kb < 4; ++kb) {
                acc[t] = __builtin_amdgcn_mfma_f32_16x16x32_f16(af[kb], bhi[t][kb], acc[t], 0, 0, 0);
                acc[t] = __builtin_amdgcn_mfma_f32_16x16x32_f16(af[kb], blo[t][kb], acc[t], 0, 0, 0);
            }
        // stage to LDS: C/D layout col=lane&15, row=q*4+r (m89/m91)
        #pragma unroll
        for (int t = 0; t < 2; ++t)
            #pragma unroll
            for (int r = 0; r < 4; ++r) {
                float v = acc[t][r] + bs[t];
                if (relu) v = fmaxf(v, 0.f);
                st[(q * 4 + r) * 36 + t * 16 + m] = v;
            }
        // coalesced readback + stores (wave-private region; lgkmcnt ordering)
        float4 v0 = *(const float4*)&st[rdrow * 36 + rdcg * 8];
        float4 v1 = *(const float4*)&st[rdrow * 36 + rdcg * 8 + 4];
        size_t gbase = (size_t)(row0 + rdrow) * 128 + pair * 32 + rdcg * 8;
        U16x8 p;
        p.s[0] = f2h(v0.x); p.s[1] = f2h(v0.y); p.s[2] = f2h(v0.z); p.s[3] = f2h(v0.w);
        p.s[4] = f2h(v1.x); p.s[5] = f2h(v1.y); p.s[6] = f2h(v1.z); p.s[7] = f2h(v1.w);
        *(uint4*)(outh + gbase) = p.u;
        if (outf) {
            *(float4*)(outf + gbase) = v0;
            *(float4*)(outf + gbase + 4) = v1;
        }
    }
}

// ---------------- graph pooling from fp16 embeds ----------------
__device__ __forceinline__ int lbound(const int* b, int n, int v) {
    int lo = 0, hi = n;
    while (lo < hi) { int mid = (lo + hi) >> 1; if (b[mid] < v) lo = mid + 1; else hi = mid; }
    return lo;
}

__global__ __launch_bounds__(128) void k_pool_partial(const u16* __restrict__ embH,
                                                      const int* __restrict__ batch,
                                                      float* __restrict__ ps_tmp) {
    int g = blockIdx.x >> 3, s = blockIdx.x & 7, t = threadIdx.x;
    int lo = lbound(batch, NN, g);
    int hi = lbound(batch, NN, g + 1);
    float acc = 0.f;
    for (int n = lo + s; n < hi; n += 8) {
        size_t base = (size_t)n * 128 + t;
        #pragma unroll
        for (int e = 0; e < 5; ++e)
            acc += h2f(embH[(size_t)e * NN * 128 + base]);
    }
    atomicAdd(&ps_tmp[g * 128 + t], acc);
}

// ---------------- head: pooled_sum -> lin1 -> lin2 -> softmax ----------------
__global__ __launch_bounds__(128) void k_final(const float* __restrict__ ps_tmp,
                                               const float* __restrict__ W1, const float* __restrict__ b1,
                                               const float* __restrict__ W2, const float* __restrict__ b2,
                                               float* __restrict__ out) {
    int g = blockIdx.x, t = threadIdx.x;
    __shared__ float ps[128], l1[128], l2[8];
    float v = ps_tmp[g * 128 + t];
    ps[t] = v;
    out[OFF_PS + (size_t)g * 128 + t] = v;
    __syncthreads();
    float a = b1[t];
    #pragma unroll 8
    for (int k = 0; k < 128; ++k) a += ps[k] * W1[t * 128 + k];
    a = fmaxf(a, 0.f);
    l1[t] = a;
    out[OFF_L1  + (size_t)g * 128 + t] = a;
    out[OFF_L1D + (size_t)g * 128 + t] = a;
    __syncthreads();
    if (t < 8) {
        float a2 = b2[t];
        #pragma unroll 8
        for (int k = 0; k < 128; ++k) a2 += l1[k] * W2[t * 128 + k];
        l2[t] = a2;
        out[OFF_L2 + (size_t)g * 8 + t] = a2;
    }
    __syncthreads();
    if (t == 0) {
        float mx = l2[0];
        for (int j = 1; j < 8; ++j) mx = fmaxf(mx, l2[j]);
        float e[8], s = 0.f;
        for (int j = 0; j < 8; ++j) { e[j] = __expf(l2[j] - mx); s += e[j]; }
        float inv = 1.f / s;
        for (int j = 0; j < 8; ++j) out[OFF_SOFT + (size_t)g * 8 + j] = e[j] * inv;
    }
}

extern "C" void kernel_launch(void* const* d_in, const int* in_sizes, int n_in,
                              void* d_out, int out_size, void* d_ws, size_t ws_size,
                              hipStream_t stream) {
    const float* x       = (const float*)d_in[0];
    const int*   ei      = (const int*)d_in[1];
    const float* emask   = (const float*)d_in[2];
    const int*   batch   = (const int*)d_in[3];
    const float* eps     = (const float*)d_in[4];
    const float* W_first = (const float*)d_in[5];
    const float* b_first = (const float*)d_in[6];
    const float* gin_W   = (const float*)d_in[7];
    const float* gin_b   = (const float*)d_in[8];
    const float* W1      = (const float*)d_in[9];
    const float* b1      = (const float*)d_in[10];
    const float* W2      = (const float*)d_in[11];
    const float* b2      = (const float*)d_in[12];
    float* out = (float*)d_out;

    char* ws = (char*)d_ws;
    const size_t HB = (size_t)NN * 128 * 2;       // 25.6 MB per fp16 node buffer
    u16* embH = (u16*)(ws);                       // 5 contiguous embed buffers
    size_t o = 5 * HB;
    u16* bufP = (u16*)(ws + o); o += HB;
    u16* bufT = (u16*)(ws + o); o += HB;
    int* cnt  = (int*)(ws + o); o += 400000;
    int* cur  = (int*)(ws + o); o += 400000;
    float* ps_tmp = (float*)(ws + o); o += (size_t)NG * DH * 4;
    int* rp   = (int*)(ws + o); o += 400064;      // NN+1 ints, padded
    int* bsum = (int*)(ws + o); o += 512;
    int* ci   = (int*)(ws + o); o += (size_t)NE * 4;
    float* wv = (float*)(ws + o); o += (size_t)NE * 4;

    // one memset covers cnt + cur + ps_tmp (adjacent)
    hipMemsetAsync(cnt, 0, 400000 + 400000 + (size_t)NG * DH * 4, stream);

    // CSR build
    k_hist<<<NE / 256, 256, 0, stream>>>(ei, cnt);
    k_scan1<<<98, 256, 0, stream>>>(cnt, rp, bsum);
    k_scan2<<<1, 128, 0, stream>>>(bsum, 98);
    k_scan3<<<98, 256, 0, stream>>>(rp, bsum);
    k_scatter<<<NE / 256, 256, 0, stream>>>(ei, emask, rp, cur, ci, wv);

    // first linear: x (fp32, converted in-kernel) -> embH[0] (+ embeds[0] fp32)
    k_gemm<<<1024, 256, 0, stream>>>(nullptr, x, W_first, b_first, embH,
                                     out + OFF_EMB, 0, NN);

    for (int l = 0; l < NL; ++l) {
        k_agg<<<NN / 4, 256, 0, stream>>>(embH + (size_t)l * NN * 128, bufP, rp, ci, wv, eps, l);
        k_gemm<<<1024, 256, 0, stream>>>(bufP, nullptr,
                                         gin_W + (size_t)(l * 2 + 0) * 128 * 128,
                                         gin_b + (size_t)(l * 2 + 0) * 128,
                                         bufT, nullptr, 1, NN);
        k_gemm<<<1024, 256, 0, stream>>>(bufT, nullptr,
                                         gin_W + (size_t)(l * 2 + 1) * 128 * 128,
                                         gin_b + (size_t)(l * 2 + 1) * 128,
                                         embH + (size_t)(l + 1) * NN * 128,
                                         out + OFF_EMB + (size_t)(l + 1) * NN * 128, 1, NN);
    }

    k_pool_partial<<<NG * 8, 128, 0, stream>>>(embH, batch, ps_tmp);
    k_final<<<NG, 128, 0, stream>>>(ps_tmp, W1, b1, W2, b2, out);
}